// Round 8
// baseline (368.905 us; speedup 1.0000x reference)
//
#include <hip/hip_runtime.h>

// 2-layer LSTM, B=1024 T=512 D=1 H=64. 256 blocks x 256 threads (4 waves), MB=4.
// R7 structure (4x row-dup, zero shuffles, 2 points/lane, x2 unroll, pipelined ini)
// + R8: attack the in-order MFMA structural hazard:
//  - per-gate exp2 moved INTO the MFMA loop (independent per gate)
//  - sched_group_barrier fine pattern 24 x {1 MFMA, 2 VALU} so selects/exps
//    issue in the matrix-pipe shadows instead of after all 24 MFMAs
//  - bias back in MFMA C-in (ini = fma(x,w,b0); cini1 for L1) - no post-adds
// LDS H bytes: L*1024 + par*512 + chunk*64 + b*16 + (unit&7)*2  (same as R5)

typedef _Float16 f16x8 __attribute__((ext_vector_type(8)));
typedef float f32x4 __attribute__((ext_vector_type(4)));

#define TSTEPS 512
#define L2E 1.44269504088896340736f

__device__ __forceinline__ float lstm_point(float ai, float af, float ag, float ao,
                                            float& c) {
    // ai,af,ao pre-scaled by -log2e ; ag by +2log2e
    const float p  = __builtin_amdgcn_exp2f(ai);   // e^-i
    const float s_ = __builtin_amdgcn_exp2f(af);   // e^-f
    const float r_ = __builtin_amdgcn_exp2f(ag);   // e^2g
    const float v  = __builtin_amdgcn_exp2f(ao);   // e^-o
    const float m1 = (1.f + p) * (1.f + r_);
    const float R  = __builtin_amdgcn_rcpf(m1 * (1.f + s_));
    const float f  = m1 * R;                       // sigmoid(f)
    const float ig = (r_ - 1.f) * ((1.f + s_) * R);// sigmoid(i)*tanh(g)
    const float cc = __builtin_fmaf(f, c, ig);
    c = cc;
    const float w  = __builtin_amdgcn_exp2f(cc * (2.f * L2E));
    return (w - 1.f) * __builtin_amdgcn_rcpf((1.f + v) * (1.f + w));
}

// combine from precomputed per-gate exps: e = {p, s_, r_, v}
__device__ __forceinline__ float lstm_tail(const float e0, const float e1,
                                           const float e2, const float e3,
                                           float& c) {
    const float m1 = (1.f + e0) * (1.f + e2);
    const float R  = __builtin_amdgcn_rcpf(m1 * (1.f + e1));
    const float f  = m1 * R;
    const float ig = (e2 - 1.f) * ((1.f + e1) * R);
    const float cc = __builtin_fmaf(f, c, ig);
    c = cc;
    const float w  = __builtin_amdgcn_exp2f(cc * (2.f * L2E));
    return (w - 1.f) * __builtin_amdgcn_rcpf((1.f + e3) * (1.f + w));
}

__global__ __launch_bounds__(256, 1) void lstm2_kernel(
    const float* __restrict__ x,
    const float* __restrict__ W_ih0, const float* __restrict__ W_hh0,
    const float* __restrict__ b_ih0, const float* __restrict__ b_hh0,
    const float* __restrict__ W_ih1, const float* __restrict__ W_hh1,
    const float* __restrict__ b_ih1, const float* __restrict__ b_hh1,
    const float* __restrict__ W_fc,  const float* __restrict__ b_fc,
    float* __restrict__ out)
{
    __shared__ alignas(16) _Float16 H[2][2][256];
    __shared__ alignas(16) float    xl[2][64][4];   // [buf][step][batch]

    const int tid  = (int)threadIdx.x;
    const int lane = tid & 63;
    const int w    = tid >> 6;          // wave: units w*16..w*16+15
    const int c    = lane & 15;
    const int quad = lane >> 4;         // 0..3
    const int L    = quad >> 1;         // lane's layer
    const int bh   = quad & 1;          // lane's batch-half (b = 2*bh + r)
    const int j    = (w << 4) | c;      // lane's hidden unit
    const int b0   = (int)blockIdx.x * 4;

    const int rdOff = quad * 64 + (c & 3) * 16;     // A-frag: h[c&3][quad*8+q]
    const int wOff0 = (j >> 3) * 64 + (bh * 2 + 0) * 16 + (j & 7) * 2;
    const int wOff1 = (j >> 3) * 64 + (bh * 2 + 1) * 16 + (j & 7) * 2;

    // ---- per-lane weight fragments ----
    float biasc0[4], wih0c[4];
    f32x4 cini1[4];               // L1 C-in = splat of scaled bias
    f16x8 bf0[4][2];              // W_hh0, K=64
    f16x8 bf1[4][4];              // [W_ih1 | W_hh1], K=128

#pragma unroll
    for (int g = 0; g < 4; ++g) {
        const int n = j + 64 * g;
        const float sg = (g == 2) ? (2.0f * L2E) : (-L2E);
        biasc0[g] = sg * (b_ih0[n] + b_hh0[n]);
        wih0c[g]  = sg * W_ih0[n];                 // D == 1
        const float bb1 = sg * (b_ih1[n] + b_hh1[n]);
        cini1[g][0] = bb1; cini1[g][1] = bb1; cini1[g][2] = bb1; cini1[g][3] = bb1;
#pragma unroll
        for (int kb = 0; kb < 2; ++kb) {
            const float* p = W_hh0 + n * 64 + kb * 32 + quad * 8;
#pragma unroll
            for (int q = 0; q < 8; ++q) bf0[g][kb][q] = (_Float16)(p[q] * sg);
        }
#pragma unroll
        for (int kb = 0; kb < 4; ++kb) {
            const int kk = kb * 32 + quad * 8;
            const float* p = (kk < 64) ? (W_ih1 + n * 64 + kk)
                                       : (W_hh1 + n * 64 + (kk - 64));
#pragma unroll
            for (int q = 0; q < 8; ++q) bf1[g][kb][q] = (_Float16)(p[q] * sg);
        }
    }

    // zero-init H + stage x chunk 0
    for (int i = tid; i < 1024; i += 256) ((_Float16*)H)[i] = (_Float16)0.f;
    {
        const int m = tid >> 6, i = tid & 63;      // coalesced per wave
        xl[0][i][m] = x[(b0 + m) * TSTEPS + i];
    }
    __syncthreads();

    float cst[2] = {0.f, 0.f};   // cell states for (L, 2bh) and (L, 2bh+1)

    // ---- peel t=0: h0(0) = lstm(bias + x0*w_ih); L0 lanes own it ----
    {
        const float xq0 = xl[0][0][bh * 2 + 0];
        const float xq1 = xl[0][0][bh * 2 + 1];
        float tmp0 = 0.f, tmp1 = 0.f;
        const float hv0 = lstm_point(__builtin_fmaf(xq0, wih0c[0], biasc0[0]),
                                     __builtin_fmaf(xq0, wih0c[1], biasc0[1]),
                                     __builtin_fmaf(xq0, wih0c[2], biasc0[2]),
                                     __builtin_fmaf(xq0, wih0c[3], biasc0[3]), tmp0);
        const float hv1 = lstm_point(__builtin_fmaf(xq1, wih0c[0], biasc0[0]),
                                     __builtin_fmaf(xq1, wih0c[1], biasc0[1]),
                                     __builtin_fmaf(xq1, wih0c[2], biasc0[2]),
                                     __builtin_fmaf(xq1, wih0c[3], biasc0[3]), tmp1);
        if (L == 0) {
            cst[0] = tmp0; cst[1] = tmp1;
            char* wb = (char*)H;                    // L=0, par=0
            *(_Float16*)(wb + wOff0) = (_Float16)hv0;
            *(_Float16*)(wb + wOff1) = (_Float16)hv1;
        }
    }
    __syncthreads();

    // precomputed pointers
    char* Hc = (char*)H;
    const char* rdBase = Hc + rdOff;            // + imm selects tile
    // half A (t odd):  pr=0 pr1=1 : h0 @ +0/+256, h1 @ +1536/+1792 ; parW: L?0:1
    // half B (t even): pr=1 pr1=0 : h0 @ +512/+768, h1 @ +1024/+1280 ; parW: L?1:0
    char* wA0 = Hc + (L ? 1024 : 512) + wOff0;
    char* wA1 = Hc + (L ? 1024 : 512) + wOff1;
    char* wB0 = Hc + (L ? 1536 : 0) + wOff0;
    char* wB1 = Hc + (L ? 1536 : 0) + wOff1;

    auto STEP = [&](int h0imm, int h1imm, char* wp0, char* wp1, const f32x4 (&ini)[4]) {
        const f16x8 a0 = *(const f16x8*)(rdBase + h0imm);
        const f16x8 a1 = *(const f16x8*)(rdBase + h0imm + 256);
        const f16x8 a2 = *(const f16x8*)(rdBase + h1imm);
        const f16x8 a3 = *(const f16x8*)(rdBase + h1imm + 256);
        float e0[4], e1[4];
#pragma unroll
        for (int g = 0; g < 4; ++g) {
            // layer0, step t (C-in carries x-term + bias)
            f32x4 A  = __builtin_amdgcn_mfma_f32_16x16x32_f16(a0, bf0[g][0], ini[g], 0, 0, 0);
            // layer1, step t-1 (C-in carries bias; shares a0,a1 = h0(t-1))
            f32x4 Bq = __builtin_amdgcn_mfma_f32_16x16x32_f16(a0, bf1[g][0], cini1[g], 0, 0, 0);
            A  = __builtin_amdgcn_mfma_f32_16x16x32_f16(a1, bf0[g][1], A,  0, 0, 0);
            Bq = __builtin_amdgcn_mfma_f32_16x16x32_f16(a1, bf1[g][1], Bq, 0, 0, 0);
            Bq = __builtin_amdgcn_mfma_f32_16x16x32_f16(a2, bf1[g][2], Bq, 0, 0, 0);
            Bq = __builtin_amdgcn_mfma_f32_16x16x32_f16(a3, bf1[g][3], Bq, 0, 0, 0);
            // this gate's exp can start as soon as its own MFMAs finish
            const float s0 = bh ? A[2]  : A[0];
            const float s1 = bh ? A[3]  : A[1];
            const float u0 = bh ? Bq[2] : Bq[0];
            const float u1 = bh ? Bq[3] : Bq[1];
            e0[g] = __builtin_amdgcn_exp2f(L ? u0 : s0);
            e1[g] = __builtin_amdgcn_exp2f(L ? u1 : s1);
        }
        // fine interleave: 1 MFMA : 2 VALU so selects/exps fill the matrix-pipe
        // shadows (in-order wave would otherwise stall at back-to-back MFMAs)
#pragma unroll
        for (int u = 0; u < 24; ++u) {
            __builtin_amdgcn_sched_group_barrier(0x008, 1, 0);  // 1 MFMA
            __builtin_amdgcn_sched_group_barrier(0x002, 2, 0);  // 2 VALU
        }
        const float hv0 = lstm_tail(e0[0], e0[1], e0[2], e0[3], cst[0]);
        const float hv1 = lstm_tail(e1[0], e1[1], e1[2], e1[3], cst[1]);
        *(_Float16*)wp0 = (_Float16)hv0;
        *(_Float16*)wp1 = (_Float16)hv1;
    };
    auto INI = [&](int t, f32x4 (&ini)[4]) {
        const f32x4 xv = *(const f32x4*)&xl[(t >> 6) & 1][t & 63][0];
#pragma unroll
        for (int g = 0; g < 4; ++g) {
            ini[g][0] = __builtin_fmaf(xv[0], wih0c[g], biasc0[g]);
            ini[g][1] = __builtin_fmaf(xv[1], wih0c[g], biasc0[g]);
            ini[g][2] = __builtin_fmaf(xv[2], wih0c[g], biasc0[g]);
            ini[g][3] = __builtin_fmaf(xv[3], wih0c[g], biasc0[g]);
        }
    };

    f32x4 iniN[4];
    INI(1, iniN);

    // ---- steady pairs: (t, t+1) for t = 1,3,...,509 ----
    for (int t = 1; t <= 509; t += 2) {
        // half A (t odd)
        f32x4 iniB[4];
        INI(t + 1, iniB);                          // independent: fills shadows
        STEP(0, 1536, wA0, wA1, iniN);
        __syncthreads();

        // half B (t+1 even)
        const int tB = t + 1;
        if ((tB & 63) == 32 && tB < 448) {         // stage next x chunk
            const int cn = (tB >> 6) + 1;
            const int m = tid >> 6, i = tid & 63;
            xl[cn & 1][i][m] = x[(b0 + m) * TSTEPS + cn * 64 + i];
        }
        INI(t + 2, iniN);                          // next pair's half A = step t+2
        STEP(512, 1024, wB0, wB1, iniB);
        __syncthreads();
    }

    // ---- t = 511 (odd, half-A parities), uses iniN = INI(511) ----
    STEP(0, 1536, wA0, wA1, iniN);
    __syncthreads();

    // ---- peel t=512: h1(511) only (pr=1, pr1=0); L1 lanes write ----
    {
        const f16x8 a0 = *(const f16x8*)(rdBase + 512);
        const f16x8 a1 = *(const f16x8*)(rdBase + 768);
        const f16x8 a2 = *(const f16x8*)(rdBase + 1024);
        const f16x8 a3 = *(const f16x8*)(rdBase + 1280);
        float gate0[4], gate1[4];
#pragma unroll
        for (int g = 0; g < 4; ++g) {
            f32x4 Bq = __builtin_amdgcn_mfma_f32_16x16x32_f16(a0, bf1[g][0], cini1[g], 0, 0, 0);
            Bq = __builtin_amdgcn_mfma_f32_16x16x32_f16(a1, bf1[g][1], Bq, 0, 0, 0);
            Bq = __builtin_amdgcn_mfma_f32_16x16x32_f16(a2, bf1[g][2], Bq, 0, 0, 0);
            Bq = __builtin_amdgcn_mfma_f32_16x16x32_f16(a3, bf1[g][3], Bq, 0, 0, 0);
            gate0[g] = bh ? Bq[2] : Bq[0];
            gate1[g] = bh ? Bq[3] : Bq[1];
        }
        float tmp0 = cst[0], tmp1 = cst[1];
        const float hv0 = lstm_point(gate0[0], gate0[1], gate0[2], gate0[3], tmp0);
        const float hv1 = lstm_point(gate1[0], gate1[1], gate1[2], gate1[3], tmp1);
        if (L == 1) {
            *(_Float16*)(Hc + 1536 + wOff0) = (_Float16)hv0;
            *(_Float16*)(Hc + 1536 + wOff1) = (_Float16)hv1;
        }
    }
    __syncthreads();

    // ---- epilogue: h0(511) at [L0,par1], h1(511) at [L1,par1] ----
    if (tid < 8) {
        const int which = tid >> 2, b = tid & 3;
        const char* hb = (const char*)H + which * 1024 + 512;
        float s = b_fc[0];
        for (int jj = 0; jj < 64; ++jj) {
            const int off = (jj >> 3) * 64 + b * 16 + (jj & 7) * 2;
            s += (float)*(const _Float16*)(hb + off) * W_fc[jj];
        }
        out[which * 1024 + b0 + b] = s;
    }
}

extern "C" void kernel_launch(void* const* d_in, const int* in_sizes, int n_in,
                              void* d_out, int out_size, void* d_ws, size_t ws_size,
                              hipStream_t stream) {
    (void)in_sizes; (void)n_in; (void)d_ws; (void)ws_size; (void)out_size;
    lstm2_kernel<<<256, 256, 0, stream>>>(
        (const float*)d_in[0],
        (const float*)d_in[1], (const float*)d_in[2],
        (const float*)d_in[3], (const float*)d_in[4],
        (const float*)d_in[5], (const float*)d_in[6],
        (const float*)d_in[7], (const float*)d_in[8],
        (const float*)d_in[9], (const float*)d_in[10],
        (float*)d_out);
}